// Round 1
// baseline (1123.831 us; speedup 1.0000x reference)
//
#include <hip/hip_runtime.h>
#include <math.h>

// Problem constants
#define BB 64
#define LL 24
#define DD 512
#define GG 2560        // 5*H
#define NSTEP 23       // LL-1
#define NTILES 160     // stepB n-tiles: 5120/32, full-K per tile
#define NBLK 160       // cooperative loop grid

__device__ __forceinline__ float sigm(float x) { return 1.0f / (1.0f + __expf(-x)); }

// ---------------------------------------------------------------------------
// fp32 GEMM, 128x128 tile, 8x8 microtile, conflict-free (R2 layout).
// C[m][n] = sum_k A[m][k]*W[n][k]. W = comp_W halves at n=2560.
// ---------------------------------------------------------------------------
__global__ __launch_bounds__(256) void gemm_big(const float* __restrict__ A,
                                                const float* __restrict__ Wt,
                                                float* __restrict__ O0,
                                                float* __restrict__ O1) {
    __shared__ float As[16][132];
    __shared__ float Bs[16][132];
    const int tid = threadIdx.x;
    const int n0 = blockIdx.x * 128;
    const int m0 = blockIdx.y * 128;
    const int tn = tid & 15;
    const int tm = tid >> 4;

    float acc[8][8];
#pragma unroll
    for (int y = 0; y < 8; ++y)
#pragma unroll
        for (int x = 0; x < 8; ++x) acc[y][x] = 0.f;

    for (int kt = 0; kt < 512; kt += 16) {
#pragma unroll
        for (int ii = 0; ii < 2; ++ii) {
            int idx = tid + ii * 256;
            int r = idx >> 2, c4 = idx & 3;
            float4 v = *(const float4*)(A + (size_t)(m0 + r) * DD + kt + c4 * 4);
            As[c4 * 4 + 0][r] = v.x;
            As[c4 * 4 + 1][r] = v.y;
            As[c4 * 4 + 2][r] = v.z;
            As[c4 * 4 + 3][r] = v.w;
        }
#pragma unroll
        for (int ii = 0; ii < 2; ++ii) {
            int idx = tid + ii * 256;
            int r = idx >> 2, c4 = idx & 3;
            int n = n0 + r;
            const float* wrow = (n < GG) ? (Wt + (size_t)n * (2 * DD))
                                         : (Wt + (size_t)(n - GG) * (2 * DD) + DD);
            float4 v = *(const float4*)(wrow + kt + c4 * 4);
            Bs[c4 * 4 + 0][r] = v.x;
            Bs[c4 * 4 + 1][r] = v.y;
            Bs[c4 * 4 + 2][r] = v.z;
            Bs[c4 * 4 + 3][r] = v.w;
        }
        __syncthreads();
#pragma unroll
        for (int k = 0; k < 16; ++k) {
            float4 a0 = *(const float4*)&As[k][tm * 8];
            float4 a1 = *(const float4*)&As[k][tm * 8 + 4];
            float4 b0 = *(const float4*)&Bs[k][tn * 4];
            float4 b1 = *(const float4*)&Bs[k][64 + tn * 4];
            float av[8] = {a0.x, a0.y, a0.z, a0.w, a1.x, a1.y, a1.z, a1.w};
            float bv[8] = {b0.x, b0.y, b0.z, b0.w, b1.x, b1.y, b1.z, b1.w};
#pragma unroll
            for (int y = 0; y < 8; ++y)
#pragma unroll
                for (int x = 0; x < 8; ++x) acc[y][x] += av[y] * bv[x];
        }
        __syncthreads();
    }

#pragma unroll
    for (int y = 0; y < 8; ++y) {
        const int m = m0 + tm * 8 + y;
#pragma unroll
        for (int g = 0; g < 2; ++g) {
            int n = n0 + g * 64 + tn * 4;
            float4 v;
            v.x = acc[y][g * 4 + 0];
            v.y = acc[y][g * 4 + 1];
            v.z = acc[y][g * 4 + 2];
            v.w = acc[y][g * 4 + 3];
            float* dst = (n < GG) ? (O0 + (size_t)m * GG + n)
                                  : (O1 + (size_t)m * GG + (n - GG));
            *(float4*)dst = v;
        }
    }
}

// ---------------------------------------------------------------------------
// fp32 GEMM, 64x128 tile — word projection. +bias, out h|c split at n=512.
// ---------------------------------------------------------------------------
__global__ __launch_bounds__(256) void gemm64w(const float* __restrict__ A,
                                               const float* __restrict__ Wt,
                                               const float* __restrict__ bias,
                                               float* __restrict__ O0,
                                               float* __restrict__ O1) {
    __shared__ float As[16][68];
    __shared__ float Bs[16][132];
    const int tid = threadIdx.x;
    const int n0 = blockIdx.x * 128;
    const int m0 = blockIdx.y * 64;
    const int tn = tid & 15;
    const int tm = tid >> 4;

    float acc[4][8];
#pragma unroll
    for (int y = 0; y < 4; ++y)
#pragma unroll
        for (int x = 0; x < 8; ++x) acc[y][x] = 0.f;

    for (int kt = 0; kt < 512; kt += 16) {
        {
            int r = tid >> 2, c4 = tid & 3;
            float4 v = *(const float4*)(A + (size_t)(m0 + r) * DD + kt + c4 * 4);
            As[c4 * 4 + 0][r] = v.x;
            As[c4 * 4 + 1][r] = v.y;
            As[c4 * 4 + 2][r] = v.z;
            As[c4 * 4 + 3][r] = v.w;
        }
#pragma unroll
        for (int ii = 0; ii < 2; ++ii) {
            int idx = tid + ii * 256;
            int r = idx >> 2, c4 = idx & 3;
            float4 v = *(const float4*)(Wt + (size_t)(n0 + r) * DD + kt + c4 * 4);
            Bs[c4 * 4 + 0][r] = v.x;
            Bs[c4 * 4 + 1][r] = v.y;
            Bs[c4 * 4 + 2][r] = v.z;
            Bs[c4 * 4 + 3][r] = v.w;
        }
        __syncthreads();
#pragma unroll
        for (int k = 0; k < 16; ++k) {
            float4 a = *(const float4*)&As[k][tm * 4];
            float4 b0 = *(const float4*)&Bs[k][tn * 4];
            float4 b1 = *(const float4*)&Bs[k][64 + tn * 4];
            float av[4] = {a.x, a.y, a.z, a.w};
            float bv[8] = {b0.x, b0.y, b0.z, b0.w, b1.x, b1.y, b1.z, b1.w};
#pragma unroll
            for (int y = 0; y < 4; ++y)
#pragma unroll
                for (int x = 0; x < 8; ++x) acc[y][x] += av[y] * bv[x];
        }
        __syncthreads();
    }

#pragma unroll
    for (int y = 0; y < 4; ++y) {
        const int m = m0 + tm * 4 + y;
#pragma unroll
        for (int g = 0; g < 2; ++g) {
            int n = n0 + g * 64 + tn * 4;
            float4 v;
            v.x = acc[y][g * 4 + 0] + bias[n + 0];
            v.y = acc[y][g * 4 + 1] + bias[n + 1];
            v.z = acc[y][g * 4 + 2] + bias[n + 2];
            v.w = acc[y][g * 4 + 3] + bias[n + 3];
            float* dst = (n < DD) ? (O0 + (size_t)m * DD + n)
                                  : (O1 + (size_t)m * DD + (n - DD));
            *(float4*)dst = v;
        }
    }
}

// ---------------------------------------------------------------------------
// half-block (128-lane) candidate scorer, wave-reduced to lanes (tid&63)==0
// ---------------------------------------------------------------------------
__device__ __forceinline__ float half_dot(const float* __restrict__ ar,
                                          const float* __restrict__ br,
                                          const float* __restrict__ cb,
                                          const float* __restrict__ cl,
                                          const float* __restrict__ cr,
                                          const float* __restrict__ q, int lane) {
    float part = 0.f;
#pragma unroll
    for (int d = lane; d < DD; d += 128) {
        float gi = ar[d] + br[d] + cb[d];
        float gfl = ar[DD + d] + br[DD + d] + cb[DD + d];
        float gfr = ar[2 * DD + d] + br[2 * DD + d] + cb[2 * DD + d];
        float gu = ar[3 * DD + d] + br[3 * DD + d] + cb[3 * DD + d];
        float go = ar[4 * DD + d] + br[4 * DD + d] + cb[4 * DD + d];
        float nc = cl[d] * sigm(gfl + 1.f) + cr[d] * sigm(gfr + 1.f) + tanhf(gu) * sigm(gi);
        part += sigm(go) * tanhf(nc) * q[d];
    }
#pragma unroll
    for (int off = 32; off; off >>= 1) part += __shfl_down(part, off);
    return part;
}

// gate pair
__device__ __forceinline__ void gate2n(const float* __restrict__ ar,
                                       const float* __restrict__ br,
                                       const float* __restrict__ cb,
                                       const float* __restrict__ cl,
                                       const float* __restrict__ cr, int d,
                                       float nh[2], float nc[2]) {
    float2 A0 = *(const float2*)(ar + d),          B0 = *(const float2*)(br + d);
    float2 A1 = *(const float2*)(ar + DD + d),     B1 = *(const float2*)(br + DD + d);
    float2 A2 = *(const float2*)(ar + 2 * DD + d), B2 = *(const float2*)(br + 2 * DD + d);
    float2 A3 = *(const float2*)(ar + 3 * DD + d), B3 = *(const float2*)(br + 3 * DD + d);
    float2 A4 = *(const float2*)(ar + 4 * DD + d), B4 = *(const float2*)(br + 4 * DD + d);
    float2 C0 = *(const float2*)(cb + d);
    float2 C1 = *(const float2*)(cb + DD + d);
    float2 C2 = *(const float2*)(cb + 2 * DD + d);
    float2 C3 = *(const float2*)(cb + 3 * DD + d);
    float2 C4 = *(const float2*)(cb + 4 * DD + d);
    float2 CL = *(const float2*)(cl + d);
    float2 CR = *(const float2*)(cr + d);
    float gi0 = A0.x + B0.x + C0.x, gi1 = A0.y + B0.y + C0.y;
    float gfl0 = A1.x + B1.x + C1.x, gfl1 = A1.y + B1.y + C1.y;
    float gfr0 = A2.x + B2.x + C2.x, gfr1 = A2.y + B2.y + C2.y;
    float gu0 = A3.x + B3.x + C3.x, gu1 = A3.y + B3.y + C3.y;
    float go0 = A4.x + B4.x + C4.x, go1 = A4.y + B4.y + C4.y;
    nc[0] = CL.x * sigm(gfl0 + 1.f) + CR.x * sigm(gfr0 + 1.f) + tanhf(gu0) * sigm(gi0);
    nc[1] = CL.y * sigm(gfl1 + 1.f) + CR.y * sigm(gfr1 + 1.f) + tanhf(gu1) * sigm(gi1);
    nh[0] = sigm(go0) * tanhf(nc[0]);
    nh[1] = sigm(go1) * tanhf(nc[1]);
}

// ---------------------------------------------------------------------------
// initial scores: grid (12, 64); each block scores 2 candidates (half-block)
// Also zeroes the grid-barrier state for the following cooperative kernel.
// ---------------------------------------------------------------------------
__global__ __launch_bounds__(256) void scoreall_k(const float* __restrict__ acache,
                                                  const float* __restrict__ bcache,
                                                  const float* __restrict__ cbuf,
                                                  const float* __restrict__ compb,
                                                  const float* __restrict__ q,
                                                  float* __restrict__ scores_g,
                                                  int* __restrict__ bar) {
    __shared__ float red_s[4];
    const int tid = threadIdx.x;
    const int b = blockIdx.y;
    const int p = blockIdx.x * 2 + (tid >> 7);
    if (blockIdx.x == 0 && blockIdx.y == 0 && tid == 0) { bar[0] = 0; bar[32] = 0; }
    const bool valid = p < NSTEP;
    float w = 0.f;
    if (valid) {
        w = half_dot(acache + (size_t)(b * LL + p) * GG,
                     bcache + (size_t)(b * LL + p + 1) * GG, compb,
                     cbuf + (size_t)(b * LL + p) * DD,
                     cbuf + (size_t)(b * LL + p + 1) * DD, q, tid & 127);
    }
    if ((tid & 63) == 0) red_s[tid >> 6] = w;
    __syncthreads();
    if ((tid == 0 || tid == 128) && valid) {
        int base = tid >> 6;
        scores_g[b * NSTEP + p] = red_s[base] + red_s[base + 1];
    }
}

// ---------------------------------------------------------------------------
// device-scope sense(generation)-reversing grid barrier.
// bar[0] = arrival counter, bar[32] = generation (128 B apart).
// ---------------------------------------------------------------------------
__device__ __forceinline__ void gridbar(int* cnt, int* gen, int nblk) {
    __syncthreads();
    if (threadIdx.x == 0) {
        __threadfence();   // release prior global writes (device scope)
        int g = __hip_atomic_load(gen, __ATOMIC_RELAXED, __HIP_MEMORY_SCOPE_AGENT);
        int prev = __hip_atomic_fetch_add(cnt, 1, __ATOMIC_ACQ_REL, __HIP_MEMORY_SCOPE_AGENT);
        if (prev == nblk - 1) {
            // all arrived: reset counter BEFORE bumping generation
            __hip_atomic_store(cnt, 0, __ATOMIC_RELAXED, __HIP_MEMORY_SCOPE_AGENT);
            __hip_atomic_fetch_add(gen, 1, __ATOMIC_RELEASE, __HIP_MEMORY_SCOPE_AGENT);
        } else {
            while (__hip_atomic_load(gen, __ATOMIC_RELAXED, __HIP_MEMORY_SCOPE_AGENT) == g) {
                __builtin_amdgcn_s_sleep(1);
            }
        }
        __threadfence();   // acquire side
    }
    __syncthreads();
}

// ---------------------------------------------------------------------------
// Persistent cooperative kernel: the entire 23-step merge loop.
//  - blocks 0..63: phase A (rescore -> argmax -> merge) for batch b = bid,
//    with per-batch scores/seq/kp persistent in LDS.
//  - all 160 blocks: phase B (a/b GEMM for merged rows), comp_W 32-col slice
//    persistent in LDS (loaded once).
// Sequence per step i: A(i) | bar | B(i) | bar   (B and bars skipped at i=22).
// ---------------------------------------------------------------------------
__global__ __launch_bounds__(256) void loop_k(
    const int* __restrict__ length, float* cbuf, float* acache, float* bcache,
    float* hout, const float* __restrict__ scores_g, int* msel_g,
    const float* __restrict__ compb, const float* __restrict__ q,
    const float* __restrict__ comp_W, float* out, int* bar) {

    __shared__ float Ws[512][36];   // persistent W slice: [k][n], 72 KB
    __shared__ float As[128][68];   // hout staging chunk
    __shared__ float sc_l[32];      // persistent per-batch scores (blocks < 64)
    __shared__ int   seq_l[32];     // persistent per-batch sequence
    __shared__ float red_s[4];
    __shared__ int   k_sh;
    __shared__ int   kp_sh;
    __shared__ int   msel_s[BB];

    const int tid = threadIdx.x;
    const int bid = blockIdx.x;
    const int lenb = (bid < BB) ? length[bid] : 0;

    // ---- one-time: load this block's 32-column W slice into LDS ----
    {
        const int swn = tid & 31, swk = tid >> 5;   // 32 n-rows x 8 k-groups
        int n = bid * 32 + swn;
        const float* wrow = (n < GG) ? (comp_W + (size_t)n * (2 * DD))
                                     : (comp_W + (size_t)(n - GG) * (2 * DD) + DD);
#pragma unroll
        for (int j = 0; j < 16; ++j) {
            int kl = swk * 64 + j * 4;
            float4 v = *(const float4*)(wrow + kl);
            Ws[kl + 0][swn] = v.x;
            Ws[kl + 1][swn] = v.y;
            Ws[kl + 2][swn] = v.z;
            Ws[kl + 3][swn] = v.w;
        }
    }
    // first __syncthreads inside phase B (or phase A) orders Ws before use.

    for (int i = 0; i < NSTEP; ++i) {
        // ================= phase A (blocks 0..63) =================
        if (bid < BB) {
            const int b = bid;
            const int ncand = NSTEP - i;
            if (i == 0) {
                if (tid < LL) seq_l[tid] = tid;
                if (tid < NSTEP) sc_l[tid] = scores_g[b * NSTEP + tid];
                if (tid == 0) kp_sh = 0;
            }
            __syncthreads();
            const int kp = kp_sh;

            if (i > 0 && i < lenb) {  // rescore candidates kp-1, kp
                int p = (tid < 128) ? (kp - 1) : kp;
                bool valid = (p >= 0) && (p < ncand);
                float w = 0.f;
                if (valid) {
                    int sl = seq_l[p], sr = seq_l[p + 1];
                    const float* ar = acache + (size_t)(b * LL + sl) * GG;
                    const float* br = bcache + (size_t)(b * LL + sr) * GG;
                    const float* cl = cbuf + (size_t)(b * LL + sl) * DD;
                    const float* cr = cbuf + (size_t)(b * LL + sr) * DD;
#pragma unroll
                    for (int pass = 0; pass < 2; ++pass) {
                        int d = pass * 256 + (tid & 127) * 2;
                        float nh[2], nc[2];
                        gate2n(ar, br, compb, cl, cr, d, nh, nc);
                        float2 Q = *(const float2*)(q + d);
                        w += nh[0] * Q.x + nh[1] * Q.y;
                    }
#pragma unroll
                    for (int off = 32; off; off >>= 1) w += __shfl_down(w, off);
                }
                if ((tid & 63) == 0) red_s[tid >> 6] = w;
                __syncthreads();
                if (tid == 0) {
                    if (kp - 1 >= 0) sc_l[kp - 1] = red_s[0] + red_s[1];
                    if (kp < ncand) sc_l[kp] = red_s[2] + red_s[3];
                }
                __syncthreads();
            }

            if (i + 1 < lenb) {
                if (tid == 0) {
                    const int vmax = lenb - i - 2;
                    int k = 0;
                    float best = sc_l[0];
                    for (int pp = 1; pp <= vmax; ++pp)
                        if (sc_l[pp] > best) { best = sc_l[pp]; k = pp; }
                    k_sh = k;
                }
                __syncthreads();
                const int k = k_sh;
                const int sl = seq_l[k], sr = seq_l[k + 1];
                const float* ar = acache + (size_t)(b * LL + sl) * GG;
                const float* br = bcache + (size_t)(b * LL + sr) * GG;
                const float* cl = cbuf + (size_t)(b * LL + sl) * DD;
                const float* cr = cbuf + (size_t)(b * LL + sr) * DD;
                {
                    const int d = 2 * tid;
                    float nh[2], nc[2];
                    gate2n(ar, br, compb, cl, cr, d, nh, nc);
                    *(float2*)(cbuf + (size_t)(b * LL + sl) * DD + d) = make_float2(nc[0], nc[1]);
                    *(float2*)(hout + (size_t)b * DD + d) = make_float2(nh[0], nh[1]);
                    if (i == NSTEP - 1)
                        *(float2*)(out + (size_t)b * DD + d) = make_float2(nh[0], nh[1]);
                }
                float sv = (tid + 1 < ncand) ? sc_l[tid + 1] : 0.f;
                int qv = (tid + 1 < LL - i) ? seq_l[tid + 1] : 0;
                __syncthreads();
                if (tid >= k + 1 && tid <= ncand - 2) sc_l[tid] = sv;
                if (tid >= k + 1 && tid <= LL - i - 2) seq_l[tid] = qv;
                if (tid == 0) { kp_sh = k; msel_g[b] = sl; }
            } else if (i == NSTEP - 1) {
                const int d = 2 * tid;
                *(float2*)(out + (size_t)b * DD + d) = *(const float2*)(hout + (size_t)b * DD + d);
            }
        }

        if (i < NSTEP - 1) {
            gridbar(&bar[0], &bar[32], NBLK);

            // ================= phase B (all 160 blocks) =================
            {
                if (tid < BB) msel_s[tid] = msel_g[tid];
                const int sar = tid & 63, sak = tid >> 6;   // A staging
                const int tn = tid & 15, tm = tid >> 4;     // compute 64m x 32n
                const float* arow = hout + (size_t)sar * DD;
                float acc[4][2];
#pragma unroll
                for (int y = 0; y < 4; ++y) { acc[y][0] = 0.f; acc[y][1] = 0.f; }
                float4 ra[8];
#pragma unroll
                for (int j = 0; j < 8; ++j) ra[j] = *(const float4*)(arow + sak * 32 + j * 4);
#pragma unroll 1
                for (int c = 0; c < 4; ++c) {
                    __syncthreads();
#pragma unroll
                    for (int j = 0; j < 8; ++j) {   // A: 64 rows x 128 k
                        int kl = sak * 32 + j * 4;
                        As[kl + 0][sar] = ra[j].x;
                        As[kl + 1][sar] = ra[j].y;
                        As[kl + 2][sar] = ra[j].z;
                        As[kl + 3][sar] = ra[j].w;
                    }
                    if (c < 3) {  // prefetch next hout chunk over compute
                        int kb = (c + 1) * 128;
#pragma unroll
                        for (int j = 0; j < 8; ++j)
                            ra[j] = *(const float4*)(arow + kb + sak * 32 + j * 4);
                    }
                    __syncthreads();
                    const int kw = c * 128;
#pragma unroll 8
                    for (int k = 0; k < 128; ++k) {
                        float4 a = *(const float4*)&As[k][tm * 4];
                        float2 w = *(const float2*)&Ws[kw + k][tn * 2];
                        acc[0][0] += a.x * w.x; acc[0][1] += a.x * w.y;
                        acc[1][0] += a.y * w.x; acc[1][1] += a.y * w.y;
                        acc[2][0] += a.z * w.x; acc[2][1] += a.z * w.y;
                        acc[3][0] += a.w * w.x; acc[3][1] += a.w * w.y;
                    }
                }
                const int n0 = bid * 32 + tn * 2;
#pragma unroll
                for (int y = 0; y < 4; ++y) {
                    int m = tm * 4 + y;
                    size_t row = (size_t)(m * LL + msel_s[m]);
                    float* dst = (n0 < GG) ? (acache + row * GG + n0)
                                           : (bcache + row * GG + (n0 - GG));
                    *(float2*)dst = make_float2(acc[y][0], acc[y][1]);
                }
            }

            gridbar(&bar[0], &bar[32], NBLK);
        }
    }
}

// ---------------------------------------------------------------------------
extern "C" void kernel_launch(void* const* d_in, const int* in_sizes, int n_in, void* d_out,
                              int out_size, void* d_ws, size_t ws_size, hipStream_t stream) {
    const float* inp = (const float*)d_in[0];
    const int* length = (const int*)d_in[1];
    const float* word_W = (const float*)d_in[2];
    const float* word_b = (const float*)d_in[3];
    const float* comp_W = (const float*)d_in[4];
    const float* comp_b = (const float*)d_in[5];
    const float* comp_q = (const float*)d_in[6];
    float* out = (float*)d_out;

    float* ws = (float*)d_ws;
    size_t off = 0;
    float* hbuf = ws + off;   off += (size_t)BB * LL * DD;
    float* cbuf = ws + off;   off += (size_t)BB * LL * DD;
    float* acache = ws + off; off += (size_t)BB * LL * GG;
    float* bcache = ws + off; off += (size_t)BB * LL * GG;
    float* hout = ws + off;   off += (size_t)BB * DD;
    float* scores = ws + off; off += 2048;
    int* seq_g = (int*)(ws + off); off += BB * 32;   // (unused; layout kept)
    int* kp_g = (int*)(ws + off);  off += 64;        // (unused; layout kept)
    int* msel = (int*)(ws + off);  off += 64;
    int* bar = (int*)(ws + off);   off += 64;        // [0]=cnt, [32]=gen
    (void)ws_size; (void)in_sizes; (void)n_in; (void)out_size;
    (void)seq_g; (void)kp_g;

    // word projection: h,c = split(inp @ word_W.T + word_b)
    gemm64w<<<dim3(8, 24), 256, 0, stream>>>(inp, word_W, word_b, hbuf, cbuf);

    // a/b caches for all 1536 items (128x128 tile, 8x8 microtile)
    gemm_big<<<dim3(40, 12), 256, 0, stream>>>(hbuf, comp_W, acache, bcache);

    // initial candidate scores (+ barrier init)
    scoreall_k<<<dim3(12, 64), 256, 0, stream>>>(acache, bcache, cbuf, comp_b, comp_q,
                                                 scores, bar);

    // fused persistent 23-step loop (cooperative: 160 blocks, 1/CU guaranteed)
    {
        void* args[] = {(void*)&length, (void*)&cbuf,  (void*)&acache, (void*)&bcache,
                        (void*)&hout,   (void*)&scores,(void*)&msel,   (void*)&comp_b,
                        (void*)&comp_q, (void*)&comp_W,(void*)&out,    (void*)&bar};
        hipLaunchCooperativeKernel((const void*)loop_k, dim3(NBLK), dim3(256),
                                   args, 0, stream);
    }
}

// Round 2
// 687.968 us; speedup vs baseline: 1.6336x; 1.6336x over previous
//
#include <hip/hip_runtime.h>
#include <math.h>

// Problem constants
#define BB 64
#define LL 24
#define DD 512
#define GG 2560        // 5*H
#define NSTEP 23       // LL-1
#define NTILES 160     // stepB n-tiles: 5120/32

__device__ __forceinline__ float sigm(float x) { return 1.0f / (1.0f + __expf(-x)); }

// bf16 split helpers (RNE)
__device__ __forceinline__ unsigned short f2bf(float x) {
    unsigned u = __float_as_uint(x);
    unsigned r = (u + 0x7fff + ((u >> 16) & 1)) >> 16;
    return (unsigned short)r;
}
__device__ __forceinline__ float bf2f(unsigned short b) {
    return __uint_as_float(((unsigned)b) << 16);
}

using short8 = __attribute__((ext_vector_type(8))) short;
using f32x4 = __attribute__((ext_vector_type(4))) float;

// ---------------------------------------------------------------------------
// fp32 GEMM, 128x128 tile, 8x8 microtile (round-0 verified).
// ---------------------------------------------------------------------------
__global__ __launch_bounds__(256) void gemm_big(const float* __restrict__ A,
                                                const float* __restrict__ Wt,
                                                float* __restrict__ O0,
                                                float* __restrict__ O1) {
    __shared__ float As[16][132];
    __shared__ float Bs[16][132];
    const int tid = threadIdx.x;
    const int n0 = blockIdx.x * 128;
    const int m0 = blockIdx.y * 128;
    const int tn = tid & 15;
    const int tm = tid >> 4;

    float acc[8][8];
#pragma unroll
    for (int y = 0; y < 8; ++y)
#pragma unroll
        for (int x = 0; x < 8; ++x) acc[y][x] = 0.f;

    for (int kt = 0; kt < 512; kt += 16) {
#pragma unroll
        for (int ii = 0; ii < 2; ++ii) {
            int idx = tid + ii * 256;
            int r = idx >> 2, c4 = idx & 3;
            float4 v = *(const float4*)(A + (size_t)(m0 + r) * DD + kt + c4 * 4);
            As[c4 * 4 + 0][r] = v.x;
            As[c4 * 4 + 1][r] = v.y;
            As[c4 * 4 + 2][r] = v.z;
            As[c4 * 4 + 3][r] = v.w;
        }
#pragma unroll
        for (int ii = 0; ii < 2; ++ii) {
            int idx = tid + ii * 256;
            int r = idx >> 2, c4 = idx & 3;
            int n = n0 + r;
            const float* wrow = (n < GG) ? (Wt + (size_t)n * (2 * DD))
                                         : (Wt + (size_t)(n - GG) * (2 * DD) + DD);
            float4 v = *(const float4*)(wrow + kt + c4 * 4);
            Bs[c4 * 4 + 0][r] = v.x;
            Bs[c4 * 4 + 1][r] = v.y;
            Bs[c4 * 4 + 2][r] = v.z;
            Bs[c4 * 4 + 3][r] = v.w;
        }
        __syncthreads();
#pragma unroll
        for (int k = 0; k < 16; ++k) {
            float4 a0 = *(const float4*)&As[k][tm * 8];
            float4 a1 = *(const float4*)&As[k][tm * 8 + 4];
            float4 b0 = *(const float4*)&Bs[k][tn * 4];
            float4 b1 = *(const float4*)&Bs[k][64 + tn * 4];
            float av[8] = {a0.x, a0.y, a0.z, a0.w, a1.x, a1.y, a1.z, a1.w};
            float bv[8] = {b0.x, b0.y, b0.z, b0.w, b1.x, b1.y, b1.z, b1.w};
#pragma unroll
            for (int y = 0; y < 8; ++y)
#pragma unroll
                for (int x = 0; x < 8; ++x) acc[y][x] += av[y] * bv[x];
        }
        __syncthreads();
    }

#pragma unroll
    for (int y = 0; y < 8; ++y) {
        const int m = m0 + tm * 8 + y;
#pragma unroll
        for (int g = 0; g < 2; ++g) {
            int n = n0 + g * 64 + tn * 4;
            float4 v;
            v.x = acc[y][g * 4 + 0];
            v.y = acc[y][g * 4 + 1];
            v.z = acc[y][g * 4 + 2];
            v.w = acc[y][g * 4 + 3];
            float* dst = (n < GG) ? (O0 + (size_t)m * GG + n)
                                  : (O1 + (size_t)m * GG + (n - GG));
            *(float4*)dst = v;
        }
    }
}

// ---------------------------------------------------------------------------
// fp32 GEMM, 64x128 tile — word projection (round-0 verified).
// ---------------------------------------------------------------------------
__global__ __launch_bounds__(256) void gemm64w(const float* __restrict__ A,
                                               const float* __restrict__ Wt,
                                               const float* __restrict__ bias,
                                               float* __restrict__ O0,
                                               float* __restrict__ O1) {
    __shared__ float As[16][68];
    __shared__ float Bs[16][132];
    const int tid = threadIdx.x;
    const int n0 = blockIdx.x * 128;
    const int m0 = blockIdx.y * 64;
    const int tn = tid & 15;
    const int tm = tid >> 4;

    float acc[4][8];
#pragma unroll
    for (int y = 0; y < 4; ++y)
#pragma unroll
        for (int x = 0; x < 8; ++x) acc[y][x] = 0.f;

    for (int kt = 0; kt < 512; kt += 16) {
        {
            int r = tid >> 2, c4 = tid & 3;
            float4 v = *(const float4*)(A + (size_t)(m0 + r) * DD + kt + c4 * 4);
            As[c4 * 4 + 0][r] = v.x;
            As[c4 * 4 + 1][r] = v.y;
            As[c4 * 4 + 2][r] = v.z;
            As[c4 * 4 + 3][r] = v.w;
        }
#pragma unroll
        for (int ii = 0; ii < 2; ++ii) {
            int idx = tid + ii * 256;
            int r = idx >> 2, c4 = idx & 3;
            float4 v = *(const float4*)(Wt + (size_t)(n0 + r) * DD + kt + c4 * 4);
            Bs[c4 * 4 + 0][r] = v.x;
            Bs[c4 * 4 + 1][r] = v.y;
            Bs[c4 * 4 + 2][r] = v.z;
            Bs[c4 * 4 + 3][r] = v.w;
        }
        __syncthreads();
#pragma unroll
        for (int k = 0; k < 16; ++k) {
            float4 a = *(const float4*)&As[k][tm * 4];
            float4 b0 = *(const float4*)&Bs[k][tn * 4];
            float4 b1 = *(const float4*)&Bs[k][64 + tn * 4];
            float av[4] = {a.x, a.y, a.z, a.w};
            float bv[8] = {b0.x, b0.y, b0.z, b0.w, b1.x, b1.y, b1.z, b1.w};
#pragma unroll
            for (int y = 0; y < 4; ++y)
#pragma unroll
                for (int x = 0; x < 8; ++x) acc[y][x] += av[y] * bv[x];
        }
        __syncthreads();
    }

#pragma unroll
    for (int y = 0; y < 4; ++y) {
        const int m = m0 + tm * 4 + y;
#pragma unroll
        for (int g = 0; g < 2; ++g) {
            int n = n0 + g * 64 + tn * 4;
            float4 v;
            v.x = acc[y][g * 4 + 0] + bias[n + 0];
            v.y = acc[y][g * 4 + 1] + bias[n + 1];
            v.z = acc[y][g * 4 + 2] + bias[n + 2];
            v.w = acc[y][g * 4 + 3] + bias[n + 3];
            float* dst = (n < DD) ? (O0 + (size_t)m * DD + n)
                                  : (O1 + (size_t)m * DD + (n - DD));
            *(float4*)dst = v;
        }
    }
}

// ---------------------------------------------------------------------------
// one-time: split comp_W into bf16 hi/lo, rearranged to [5120][512]
// row n (<2560): comp_W[n][0:512] (a-part); row n>=2560: comp_W[n-2560][512:1024]
// ---------------------------------------------------------------------------
__global__ __launch_bounds__(256) void splitW_k(const float* __restrict__ comp_W,
                                                unsigned short* __restrict__ Wh,
                                                unsigned short* __restrict__ Wl) {
    int t = (blockIdx.x * 256 + threadIdx.x) * 4;   // 5120*512 elems, 4/thread
    int n = t >> 9;
    int k = t & 511;
    const float* src = (n < GG) ? (comp_W + (size_t)n * (2 * DD) + k)
                                : (comp_W + (size_t)(n - GG) * (2 * DD) + DD + k);
    float4 v = *(const float4*)src;
    ushort4 h, l;
    h.x = f2bf(v.x); l.x = f2bf(v.x - bf2f(h.x));
    h.y = f2bf(v.y); l.y = f2bf(v.y - bf2f(h.y));
    h.z = f2bf(v.z); l.z = f2bf(v.z - bf2f(h.z));
    h.w = f2bf(v.w); l.w = f2bf(v.w - bf2f(h.w));
    *(ushort4*)(Wh + t) = h;
    *(ushort4*)(Wl + t) = l;
}

// ---------------------------------------------------------------------------
// half-block (128-lane) candidate scorer
// ---------------------------------------------------------------------------
__device__ __forceinline__ float half_dot(const float* __restrict__ ar,
                                          const float* __restrict__ br,
                                          const float* __restrict__ cb,
                                          const float* __restrict__ cl,
                                          const float* __restrict__ cr,
                                          const float* __restrict__ q, int lane) {
    float part = 0.f;
#pragma unroll
    for (int d = lane; d < DD; d += 128) {
        float gi = ar[d] + br[d] + cb[d];
        float gfl = ar[DD + d] + br[DD + d] + cb[DD + d];
        float gfr = ar[2 * DD + d] + br[2 * DD + d] + cb[2 * DD + d];
        float gu = ar[3 * DD + d] + br[3 * DD + d] + cb[3 * DD + d];
        float go = ar[4 * DD + d] + br[4 * DD + d] + cb[4 * DD + d];
        float nc = cl[d] * sigm(gfl + 1.f) + cr[d] * sigm(gfr + 1.f) + tanhf(gu) * sigm(gi);
        part += sigm(go) * tanhf(nc) * q[d];
    }
#pragma unroll
    for (int off = 32; off; off >>= 1) part += __shfl_down(part, off);
    return part;
}

// gate pair
__device__ __forceinline__ void gate2n(const float* __restrict__ ar,
                                       const float* __restrict__ br,
                                       const float* __restrict__ cb,
                                       const float* __restrict__ cl,
                                       const float* __restrict__ cr, int d,
                                       float nh[2], float nc[2]) {
    float2 A0 = *(const float2*)(ar + d),          B0 = *(const float2*)(br + d);
    float2 A1 = *(const float2*)(ar + DD + d),     B1 = *(const float2*)(br + DD + d);
    float2 A2 = *(const float2*)(ar + 2 * DD + d), B2 = *(const float2*)(br + 2 * DD + d);
    float2 A3 = *(const float2*)(ar + 3 * DD + d), B3 = *(const float2*)(br + 3 * DD + d);
    float2 A4 = *(const float2*)(ar + 4 * DD + d), B4 = *(const float2*)(br + 4 * DD + d);
    float2 C0 = *(const float2*)(cb + d);
    float2 C1 = *(const float2*)(cb + DD + d);
    float2 C2 = *(const float2*)(cb + 2 * DD + d);
    float2 C3 = *(const float2*)(cb + 3 * DD + d);
    float2 C4 = *(const float2*)(cb + 4 * DD + d);
    float2 CL = *(const float2*)(cl + d);
    float2 CR = *(const float2*)(cr + d);
    float gi0 = A0.x + B0.x + C0.x, gi1 = A0.y + B0.y + C0.y;
    float gfl0 = A1.x + B1.x + C1.x, gfl1 = A1.y + B1.y + C1.y;
    float gfr0 = A2.x + B2.x + C2.x, gfr1 = A2.y + B2.y + C2.y;
    float gu0 = A3.x + B3.x + C3.x, gu1 = A3.y + B3.y + C3.y;
    float go0 = A4.x + B4.x + C4.x, go1 = A4.y + B4.y + C4.y;
    nc[0] = CL.x * sigm(gfl0 + 1.f) + CR.x * sigm(gfr0 + 1.f) + tanhf(gu0) * sigm(gi0);
    nc[1] = CL.y * sigm(gfl1 + 1.f) + CR.y * sigm(gfr1 + 1.f) + tanhf(gu1) * sigm(gi1);
    nh[0] = sigm(go0) * tanhf(nc[0]);
    nh[1] = sigm(go1) * tanhf(nc[1]);
}

// ---------------------------------------------------------------------------
// initial scores: grid (12, 64)
// ---------------------------------------------------------------------------
__global__ __launch_bounds__(256) void scoreall_k(const float* __restrict__ acache,
                                                  const float* __restrict__ bcache,
                                                  const float* __restrict__ cbuf,
                                                  const float* __restrict__ compb,
                                                  const float* __restrict__ q,
                                                  float* __restrict__ scores_g) {
    __shared__ float red_s[4];
    const int tid = threadIdx.x;
    const int b = blockIdx.y;
    const int p = blockIdx.x * 2 + (tid >> 7);
    const bool valid = p < NSTEP;
    float w = 0.f;
    if (valid) {
        w = half_dot(acache + (size_t)(b * LL + p) * GG,
                     bcache + (size_t)(b * LL + p + 1) * GG, compb,
                     cbuf + (size_t)(b * LL + p) * DD,
                     cbuf + (size_t)(b * LL + p + 1) * DD, q, tid & 127);
    }
    if ((tid & 63) == 0) red_s[tid >> 6] = w;
    __syncthreads();
    if ((tid == 0 || tid == 128) && valid) {
        int base = tid >> 6;
        scores_g[b * NSTEP + p] = red_s[base] + red_s[base + 1];
    }
}

// ---------------------------------------------------------------------------
// stepA: 64 blocks (one per batch). rescore -> argmax -> merge -> hout (+bf16
// hi/lo split for the MFMA stepB) ; shift per-batch state (global).
// ---------------------------------------------------------------------------
__global__ __launch_bounds__(256) void stepA_k(
    int i, const int* __restrict__ length, float* __restrict__ cbuf,
    const float* __restrict__ acache, const float* __restrict__ bcache,
    float* __restrict__ hout, unsigned short* __restrict__ hh,
    unsigned short* __restrict__ hl, float* __restrict__ scores_g,
    int* __restrict__ seq_g, int* __restrict__ kp_g, int* __restrict__ msel,
    const float* __restrict__ compb, const float* __restrict__ q, float* __restrict__ out) {
    __shared__ float red_s[4];
    __shared__ float sc_l[32];
    __shared__ int seq_l[32];
    __shared__ int k_sh;
    const int tid = threadIdx.x;
    const int b = blockIdx.x;
    const int lane7 = tid & 127;
    const int lenb = length[b];
    const int ncand = NSTEP - i;

    if (i == 0) {
        if (tid < LL) seq_l[tid] = tid;
    } else {
        if (tid < LL - i) seq_l[tid] = seq_g[b * 32 + tid];
    }
    if (tid < ncand) sc_l[tid] = scores_g[b * NSTEP + tid];
    __syncthreads();
    const int kp = (i > 0) ? kp_g[b] : 0;

    if (i > 0 && i < lenb) {  // rescore candidates kp-1, kp (half-block each)
        int p = (tid < 128) ? (kp - 1) : kp;
        bool valid = (p >= 0) && (p < ncand);
        float w = 0.f;
        if (valid) {
            int sl = seq_l[p], sr = seq_l[p + 1];
            const float* ar = acache + (size_t)(b * LL + sl) * GG;
            const float* br = bcache + (size_t)(b * LL + sr) * GG;
            const float* cl = cbuf + (size_t)(b * LL + sl) * DD;
            const float* cr = cbuf + (size_t)(b * LL + sr) * DD;
#pragma unroll
            for (int pass = 0; pass < 2; ++pass) {
                int d = pass * 256 + lane7 * 2;
                float nh[2], nc[2];
                gate2n(ar, br, compb, cl, cr, d, nh, nc);
                float2 Q = *(const float2*)(q + d);
                w += nh[0] * Q.x + nh[1] * Q.y;
            }
#pragma unroll
            for (int off = 32; off; off >>= 1) w += __shfl_down(w, off);
        }
        if ((tid & 63) == 0) red_s[tid >> 6] = w;
        __syncthreads();
        if (tid == 0) {
            if (kp - 1 >= 0) sc_l[kp - 1] = red_s[0] + red_s[1];
            if (kp < ncand) sc_l[kp] = red_s[2] + red_s[3];
        }
        __syncthreads();
    }

    if (i + 1 < lenb) {
        if (tid == 0) {
            const int vmax = lenb - i - 2;
            int k = 0;
            float best = sc_l[0];
            for (int pp = 1; pp <= vmax; ++pp)
                if (sc_l[pp] > best) { best = sc_l[pp]; k = pp; }
            k_sh = k;
        }
        __syncthreads();
        const int k = k_sh;
        const int sl = seq_l[k], sr = seq_l[k + 1];
        const float* ar = acache + (size_t)(b * LL + sl) * GG;
        const float* br = bcache + (size_t)(b * LL + sr) * GG;
        const float* cl = cbuf + (size_t)(b * LL + sl) * DD;
        const float* cr = cbuf + (size_t)(b * LL + sr) * DD;
        {
            const int d = 2 * tid;
            float nh[2], nc[2];
            gate2n(ar, br, compb, cl, cr, d, nh, nc);
            *(float2*)(cbuf + (size_t)(b * LL + sl) * DD + d) = make_float2(nc[0], nc[1]);
            *(float2*)(hout + (size_t)b * DD + d) = make_float2(nh[0], nh[1]);
            // bf16 hi/lo split for stepB's MFMA A-operand
            ushort2 hv, lv;
            hv.x = f2bf(nh[0]); lv.x = f2bf(nh[0] - bf2f(hv.x));
            hv.y = f2bf(nh[1]); lv.y = f2bf(nh[1] - bf2f(hv.y));
            *(ushort2*)(hh + (size_t)b * DD + d) = hv;
            *(ushort2*)(hl + (size_t)b * DD + d) = lv;
            if (i == NSTEP - 1)
                *(float2*)(out + (size_t)b * DD + d) = make_float2(nh[0], nh[1]);
        }
        float sv = (tid + 1 < ncand) ? sc_l[tid + 1] : 0.f;
        int qv = (tid + 1 < LL - i) ? seq_l[tid + 1] : 0;
        __syncthreads();
        if (tid >= k + 1 && tid <= ncand - 2) sc_l[tid] = sv;
        if (tid >= k + 1 && tid <= LL - i - 2) seq_l[tid] = qv;
        if (tid < ncand - 1) scores_g[b * NSTEP + tid] = sc_l[tid];
        if (tid < LL - i - 1) seq_g[b * 32 + tid] = seq_l[tid];
        if (tid == 0) { kp_g[b] = k; msel[b] = sl; }
    } else if (i == NSTEP - 1) {
        const int d = 2 * tid;
        *(float2*)(out + (size_t)b * DD + d) = *(const float2*)(hout + (size_t)b * DD + d);
    }
}

// ---------------------------------------------------------------------------
// stepB via bf16x3 MFMA: O[m][n] = sum_k hout[m][k]*W[n][k], M=64, N=32/block,
// K=512. 4 waves: wave w owns m-tiles {2*(w>>1), 2*(w>>1)+1} x n-tile (w&1).
// A,B fragment layout (16x16x32): lane l -> row/col = l&15, k = (l>>4)*8+j.
// C/D layout: col = lane&15, row = (lane>>4)*4 + reg  [verified m89].
// ---------------------------------------------------------------------------
__global__ __launch_bounds__(256) void stepB_mfma(
    const unsigned short* __restrict__ hh, const unsigned short* __restrict__ hl,
    const int* __restrict__ msel,
    const unsigned short* __restrict__ Wh, const unsigned short* __restrict__ Wl,
    float* __restrict__ acache, float* __restrict__ bcache) {
    __shared__ int msel_s[BB];
    const int tid = threadIdx.x;
    const int bid = blockIdx.x;
    if (tid < BB) msel_s[tid] = msel[tid];
    __syncthreads();

    const int w = tid >> 6, lane = tid & 63;
    const int mt0 = (w >> 1) * 2;           // this wave's first m-tile
    const int nt = w & 1;                   // this wave's n-tile
    const int lr = lane & 15;
    const int kg = lane >> 4;               // k-group (8 contiguous k)
    const int n = bid * 32 + nt * 16 + lr;  // global output column

    const unsigned short* wh_row = Wh + (size_t)n * DD;
    const unsigned short* wl_row = Wl + (size_t)n * DD;
    const unsigned short* a0h_row = hh + (size_t)(mt0 * 16 + lr) * DD;
    const unsigned short* a0l_row = hl + (size_t)(mt0 * 16 + lr) * DD;
    const unsigned short* a1h_row = a0h_row + 16 * DD;
    const unsigned short* a1l_row = a0l_row + 16 * DD;

    f32x4 acc0 = {0.f, 0.f, 0.f, 0.f};
    f32x4 acc1 = {0.f, 0.f, 0.f, 0.f};

#pragma unroll 4
    for (int ks = 0; ks < 16; ++ks) {
        const int kb = ks * 32 + kg * 8;
        short8 bh = *(const short8*)(wh_row + kb);
        short8 bl = *(const short8*)(wl_row + kb);
        short8 a0h = *(const short8*)(a0h_row + kb);
        short8 a0l = *(const short8*)(a0l_row + kb);
        short8 a1h = *(const short8*)(a1h_row + kb);
        short8 a1l = *(const short8*)(a1l_row + kb);
        acc0 = __builtin_amdgcn_mfma_f32_16x16x32_bf16(a0h, bh, acc0, 0, 0, 0);
        acc1 = __builtin_amdgcn_mfma_f32_16x16x32_bf16(a1h, bh, acc1, 0, 0, 0);
        acc0 = __builtin_amdgcn_mfma_f32_16x16x32_bf16(a0l, bh, acc0, 0, 0, 0);
        acc1 = __builtin_amdgcn_mfma_f32_16x16x32_bf16(a1l, bh, acc1, 0, 0, 0);
        acc0 = __builtin_amdgcn_mfma_f32_16x16x32_bf16(a0h, bl, acc0, 0, 0, 0);
        acc1 = __builtin_amdgcn_mfma_f32_16x16x32_bf16(a1h, bl, acc1, 0, 0, 0);
    }

    // write: n fixed per lane; rows m = mt*16 + kg*4 + r, scattered by msel
#pragma unroll
    for (int t = 0; t < 2; ++t) {
        f32x4 acc = t ? acc1 : acc0;
        const int mbase = (mt0 + t) * 16 + kg * 4;
#pragma unroll
        for (int r = 0; r < 4; ++r) {
            int m = mbase + r;
            size_t row = (size_t)(m * LL + msel_s[m]);
            float* dst = (n < GG) ? (acache + row * GG + n)
                                  : (bcache + row * GG + (n - GG));
            *dst = acc[r];
        }
    }
}

// ---------------------------------------------------------------------------
extern "C" void kernel_launch(void* const* d_in, const int* in_sizes, int n_in, void* d_out,
                              int out_size, void* d_ws, size_t ws_size, hipStream_t stream) {
    const float* inp = (const float*)d_in[0];
    const int* length = (const int*)d_in[1];
    const float* word_W = (const float*)d_in[2];
    const float* word_b = (const float*)d_in[3];
    const float* comp_W = (const float*)d_in[4];
    const float* comp_b = (const float*)d_in[5];
    const float* comp_q = (const float*)d_in[6];
    float* out = (float*)d_out;

    float* ws = (float*)d_ws;
    size_t off = 0;
    float* hbuf = ws + off;   off += (size_t)BB * LL * DD;
    float* cbuf = ws + off;   off += (size_t)BB * LL * DD;
    float* acache = ws + off; off += (size_t)BB * LL * GG;
    float* bcache = ws + off; off += (size_t)BB * LL * GG;
    float* hout = ws + off;   off += (size_t)BB * DD;
    float* scores = ws + off; off += 2048;
    int* seq_g = (int*)(ws + off); off += BB * 32;
    int* kp_g = (int*)(ws + off);  off += 64;
    int* msel = (int*)(ws + off);  off += 64;
    unsigned short* Wh = (unsigned short*)(ws + off); off += (size_t)5120 * DD / 2;
    unsigned short* Wl = (unsigned short*)(ws + off); off += (size_t)5120 * DD / 2;
    unsigned short* hh = (unsigned short*)(ws + off); off += (size_t)BB * DD / 2;
    unsigned short* hl = (unsigned short*)(ws + off); off += (size_t)BB * DD / 2;
    (void)ws_size; (void)in_sizes; (void)n_in; (void)out_size;

    // one-time bf16 hi/lo split of comp_W (rearranged [5120][512])
    splitW_k<<<2560, 256, 0, stream>>>(comp_W, Wh, Wl);

    // word projection: h,c = split(inp @ word_W.T + word_b)
    gemm64w<<<dim3(8, 24), 256, 0, stream>>>(inp, word_W, word_b, hbuf, cbuf);

    // a/b caches for all 1536 items
    gemm_big<<<dim3(40, 12), 256, 0, stream>>>(hbuf, comp_W, acache, bcache);

    // initial candidate scores
    scoreall_k<<<dim3(12, 64), 256, 0, stream>>>(acache, bcache, cbuf, comp_b, comp_q, scores);

    // 23 merge steps: A (select+merge) then B (bf16x3 MFMA GEMM for merged rows)
    for (int i = 0; i < NSTEP; ++i) {
        stepA_k<<<BB, 256, 0, stream>>>(i, length, cbuf, acache, bcache, hout, hh, hl,
                                        scores, seq_g, kp_g, msel, comp_b, comp_q, out);
        if (i < NSTEP - 1) {
            stepB_mfma<<<NTILES, 256, 0, stream>>>(hh, hl, msel, Wh, Wl, acache, bcache);
        }
    }
}

// Round 3
// 656.650 us; speedup vs baseline: 1.7115x; 1.0477x over previous
//
#include <hip/hip_runtime.h>
#include <math.h>

// Problem constants
#define BB 64
#define LL 24
#define DD 512
#define GG 2560        // 5*H
#define NSTEP 23       // LL-1
#define NTILES 160     // stepB n-tiles: 5120/32

__device__ __forceinline__ float sigm(float x) { return 1.0f / (1.0f + __expf(-x)); }

// bf16 split helpers (RNE)
__device__ __forceinline__ unsigned short f2bf(float x) {
    unsigned u = __float_as_uint(x);
    unsigned r = (u + 0x7fff + ((u >> 16) & 1)) >> 16;
    return (unsigned short)r;
}
__device__ __forceinline__ float bf2f(unsigned short b) {
    return __uint_as_float(((unsigned)b) << 16);
}

using short8 = __attribute__((ext_vector_type(8))) short;
using f32x4 = __attribute__((ext_vector_type(4))) float;

// ---------------------------------------------------------------------------
// one-time: split comp_W into bf16 hi/lo, rearranged to [5120][512]
// row n (<2560): comp_W[n][0:512] (a-part); row n>=2560: comp_W[n-2560][512:1024]
// ---------------------------------------------------------------------------
__global__ __launch_bounds__(256) void splitW_k(const float* __restrict__ comp_W,
                                                unsigned short* __restrict__ Wh,
                                                unsigned short* __restrict__ Wl) {
    int t = (blockIdx.x * 256 + threadIdx.x) * 4;   // 5120*512 elems, 4/thread
    int n = t >> 9;
    int k = t & 511;
    const float* src = (n < GG) ? (comp_W + (size_t)n * (2 * DD) + k)
                                : (comp_W + (size_t)(n - GG) * (2 * DD) + DD + k);
    float4 v = *(const float4*)src;
    ushort4 h, l;
    h.x = f2bf(v.x); l.x = f2bf(v.x - bf2f(h.x));
    h.y = f2bf(v.y); l.y = f2bf(v.y - bf2f(h.y));
    h.z = f2bf(v.z); l.z = f2bf(v.z - bf2f(h.z));
    h.w = f2bf(v.w); l.w = f2bf(v.w - bf2f(h.w));
    *(ushort4*)(Wh + t) = h;
    *(ushort4*)(Wl + t) = l;
}

// ---------------------------------------------------------------------------
// fp32 GEMM, 64x128 tile — word projection. h-part (n<512) is written as
// bf16 hi/lo (MFMA A-operand for gemm_big_mfma); c-part (n>=512) stays fp32.
// ---------------------------------------------------------------------------
__global__ __launch_bounds__(256) void gemm64w(const float* __restrict__ A,
                                               const float* __restrict__ Wt,
                                               const float* __restrict__ bias,
                                               unsigned short* __restrict__ Ah,
                                               unsigned short* __restrict__ Al,
                                               float* __restrict__ O1) {
    __shared__ float As[16][68];
    __shared__ float Bs[16][132];
    const int tid = threadIdx.x;
    const int n0 = blockIdx.x * 128;
    const int m0 = blockIdx.y * 64;
    const int tn = tid & 15;
    const int tm = tid >> 4;

    float acc[4][8];
#pragma unroll
    for (int y = 0; y < 4; ++y)
#pragma unroll
        for (int x = 0; x < 8; ++x) acc[y][x] = 0.f;

    for (int kt = 0; kt < 512; kt += 16) {
        {
            int r = tid >> 2, c4 = tid & 3;
            float4 v = *(const float4*)(A + (size_t)(m0 + r) * DD + kt + c4 * 4);
            As[c4 * 4 + 0][r] = v.x;
            As[c4 * 4 + 1][r] = v.y;
            As[c4 * 4 + 2][r] = v.z;
            As[c4 * 4 + 3][r] = v.w;
        }
#pragma unroll
        for (int ii = 0; ii < 2; ++ii) {
            int idx = tid + ii * 256;
            int r = idx >> 2, c4 = idx & 3;
            float4 v = *(const float4*)(Wt + (size_t)(n0 + r) * DD + kt + c4 * 4);
            Bs[c4 * 4 + 0][r] = v.x;
            Bs[c4 * 4 + 1][r] = v.y;
            Bs[c4 * 4 + 2][r] = v.z;
            Bs[c4 * 4 + 3][r] = v.w;
        }
        __syncthreads();
#pragma unroll
        for (int k = 0; k < 16; ++k) {
            float4 a = *(const float4*)&As[k][tm * 4];
            float4 b0 = *(const float4*)&Bs[k][tn * 4];
            float4 b1 = *(const float4*)&Bs[k][64 + tn * 4];
            float av[4] = {a.x, a.y, a.z, a.w};
            float bv[8] = {b0.x, b0.y, b0.z, b0.w, b1.x, b1.y, b1.z, b1.w};
#pragma unroll
            for (int y = 0; y < 4; ++y)
#pragma unroll
                for (int x = 0; x < 8; ++x) acc[y][x] += av[y] * bv[x];
        }
        __syncthreads();
    }

#pragma unroll
    for (int y = 0; y < 4; ++y) {
        const int m = m0 + tm * 4 + y;
#pragma unroll
        for (int g = 0; g < 2; ++g) {
            int n = n0 + g * 64 + tn * 4;
            float4 v;
            v.x = acc[y][g * 4 + 0] + bias[n + 0];
            v.y = acc[y][g * 4 + 1] + bias[n + 1];
            v.z = acc[y][g * 4 + 2] + bias[n + 2];
            v.w = acc[y][g * 4 + 3] + bias[n + 3];
            if (n < DD) {   // h part -> bf16 hi/lo split
                ushort4 hv, lv;
                hv.x = f2bf(v.x); lv.x = f2bf(v.x - bf2f(hv.x));
                hv.y = f2bf(v.y); lv.y = f2bf(v.y - bf2f(hv.y));
                hv.z = f2bf(v.z); lv.z = f2bf(v.z - bf2f(hv.z));
                hv.w = f2bf(v.w); lv.w = f2bf(v.w - bf2f(hv.w));
                *(ushort4*)(Ah + (size_t)m * DD + n) = hv;
                *(ushort4*)(Al + (size_t)m * DD + n) = lv;
            } else {        // c part -> fp32 cbuf
                *(float4*)(O1 + (size_t)m * DD + (n - DD)) = v;
            }
        }
    }
}

// ---------------------------------------------------------------------------
// a/b cache GEMM via bf16x3 MFMA. M=1536, N=5120, K=512.
// Grid (40, 12): 128x128 tile/block, 4 waves in 2x2, each wave 4x4 16-tiles.
// All operands row-major K-contiguous -> direct short8 fragment loads.
// Fragment layout identical to the verified stepB_mfma.
// ---------------------------------------------------------------------------
__global__ __launch_bounds__(256) void gemm_big_mfma(
    const unsigned short* __restrict__ Ah, const unsigned short* __restrict__ Al,
    const unsigned short* __restrict__ Wh, const unsigned short* __restrict__ Wl,
    float* __restrict__ O0, float* __restrict__ O1) {
    const int tid = threadIdx.x;
    const int n0 = blockIdx.x * 128;
    const int m0 = blockIdx.y * 128;
    const int w = tid >> 6, lane = tid & 63;
    const int mq = w >> 1, nq = w & 1;
    const int lr = lane & 15, kg = lane >> 4;
    const int kofs = kg * 8;

    const unsigned short* pah[4];
    const unsigned short* pal[4];
    const unsigned short* pbh[4];
    const unsigned short* pbl[4];
#pragma unroll
    for (int t = 0; t < 4; ++t) {
        int mrow = m0 + mq * 64 + t * 16 + lr;
        pah[t] = Ah + (size_t)mrow * DD + kofs;
        pal[t] = Al + (size_t)mrow * DD + kofs;
        int nrow = n0 + nq * 64 + t * 16 + lr;
        pbh[t] = Wh + (size_t)nrow * DD + kofs;
        pbl[t] = Wl + (size_t)nrow * DD + kofs;
    }

    f32x4 acc[4][4];
#pragma unroll
    for (int mt = 0; mt < 4; ++mt)
#pragma unroll
        for (int nt = 0; nt < 4; ++nt) acc[mt][nt] = (f32x4){0.f, 0.f, 0.f, 0.f};

#pragma unroll 2
    for (int ks = 0; ks < 16; ++ks) {
        const int kb = ks * 32;
        short8 ah[4], al[4], bh[4], bl[4];
#pragma unroll
        for (int t = 0; t < 4; ++t) {
            ah[t] = *(const short8*)(pah[t] + kb);
            al[t] = *(const short8*)(pal[t] + kb);
            bh[t] = *(const short8*)(pbh[t] + kb);
            bl[t] = *(const short8*)(pbl[t] + kb);
        }
#pragma unroll
        for (int mt = 0; mt < 4; ++mt)
#pragma unroll
            for (int nt = 0; nt < 4; ++nt) {
                acc[mt][nt] = __builtin_amdgcn_mfma_f32_16x16x32_bf16(al[mt], bh[nt], acc[mt][nt], 0, 0, 0);
                acc[mt][nt] = __builtin_amdgcn_mfma_f32_16x16x32_bf16(ah[mt], bl[nt], acc[mt][nt], 0, 0, 0);
                acc[mt][nt] = __builtin_amdgcn_mfma_f32_16x16x32_bf16(ah[mt], bh[nt], acc[mt][nt], 0, 0, 0);
            }
    }

    // C/D layout: col = lane&15, row = (lane>>4)*4 + reg   [verified, stepB]
#pragma unroll
    for (int mt = 0; mt < 4; ++mt) {
        const int mbase = m0 + mq * 64 + mt * 16 + kg * 4;
#pragma unroll
        for (int nt = 0; nt < 4; ++nt) {
            const int n = n0 + nq * 64 + nt * 16 + lr;
#pragma unroll
            for (int r = 0; r < 4; ++r) {
                const int m = mbase + r;
                float* dst = (n < GG) ? (O0 + (size_t)m * GG + n)
                                      : (O1 + (size_t)m * GG + (n - GG));
                *dst = acc[mt][nt][r];
            }
        }
    }
}

// ---------------------------------------------------------------------------
// half-block (128-lane) candidate scorer
// ---------------------------------------------------------------------------
__device__ __forceinline__ float half_dot(const float* __restrict__ ar,
                                          const float* __restrict__ br,
                                          const float* __restrict__ cb,
                                          const float* __restrict__ cl,
                                          const float* __restrict__ cr,
                                          const float* __restrict__ q, int lane) {
    float part = 0.f;
#pragma unroll
    for (int d = lane; d < DD; d += 128) {
        float gi = ar[d] + br[d] + cb[d];
        float gfl = ar[DD + d] + br[DD + d] + cb[DD + d];
        float gfr = ar[2 * DD + d] + br[2 * DD + d] + cb[2 * DD + d];
        float gu = ar[3 * DD + d] + br[3 * DD + d] + cb[3 * DD + d];
        float go = ar[4 * DD + d] + br[4 * DD + d] + cb[4 * DD + d];
        float nc = cl[d] * sigm(gfl + 1.f) + cr[d] * sigm(gfr + 1.f) + tanhf(gu) * sigm(gi);
        part += sigm(go) * tanhf(nc) * q[d];
    }
#pragma unroll
    for (int off = 32; off; off >>= 1) part += __shfl_down(part, off);
    return part;
}

// gate pair
__device__ __forceinline__ void gate2n(const float* __restrict__ ar,
                                       const float* __restrict__ br,
                                       const float* __restrict__ cb,
                                       const float* __restrict__ cl,
                                       const float* __restrict__ cr, int d,
                                       float nh[2], float nc[2]) {
    float2 A0 = *(const float2*)(ar + d),          B0 = *(const float2*)(br + d);
    float2 A1 = *(const float2*)(ar + DD + d),     B1 = *(const float2*)(br + DD + d);
    float2 A2 = *(const float2*)(ar + 2 * DD + d), B2 = *(const float2*)(br + 2 * DD + d);
    float2 A3 = *(const float2*)(ar + 3 * DD + d), B3 = *(const float2*)(br + 3 * DD + d);
    float2 A4 = *(const float2*)(ar + 4 * DD + d), B4 = *(const float2*)(br + 4 * DD + d);
    float2 C0 = *(const float2*)(cb + d);
    float2 C1 = *(const float2*)(cb + DD + d);
    float2 C2 = *(const float2*)(cb + 2 * DD + d);
    float2 C3 = *(const float2*)(cb + 3 * DD + d);
    float2 C4 = *(const float2*)(cb + 4 * DD + d);
    float2 CL = *(const float2*)(cl + d);
    float2 CR = *(const float2*)(cr + d);
    float gi0 = A0.x + B0.x + C0.x, gi1 = A0.y + B0.y + C0.y;
    float gfl0 = A1.x + B1.x + C1.x, gfl1 = A1.y + B1.y + C1.y;
    float gfr0 = A2.x + B2.x + C2.x, gfr1 = A2.y + B2.y + C2.y;
    float gu0 = A3.x + B3.x + C3.x, gu1 = A3.y + B3.y + C3.y;
    float go0 = A4.x + B4.x + C4.x, go1 = A4.y + B4.y + C4.y;
    nc[0] = CL.x * sigm(gfl0 + 1.f) + CR.x * sigm(gfr0 + 1.f) + tanhf(gu0) * sigm(gi0);
    nc[1] = CL.y * sigm(gfl1 + 1.f) + CR.y * sigm(gfr1 + 1.f) + tanhf(gu1) * sigm(gi1);
    nh[0] = sigm(go0) * tanhf(nc[0]);
    nh[1] = sigm(go1) * tanhf(nc[1]);
}

// ---------------------------------------------------------------------------
// initial scores: grid (12, 64)
// ---------------------------------------------------------------------------
__global__ __launch_bounds__(256) void scoreall_k(const float* __restrict__ acache,
                                                  const float* __restrict__ bcache,
                                                  const float* __restrict__ cbuf,
                                                  const float* __restrict__ compb,
                                                  const float* __restrict__ q,
                                                  float* __restrict__ scores_g) {
    __shared__ float red_s[4];
    const int tid = threadIdx.x;
    const int b = blockIdx.y;
    const int p = blockIdx.x * 2 + (tid >> 7);
    const bool valid = p < NSTEP;
    float w = 0.f;
    if (valid) {
        w = half_dot(acache + (size_t)(b * LL + p) * GG,
                     bcache + (size_t)(b * LL + p + 1) * GG, compb,
                     cbuf + (size_t)(b * LL + p) * DD,
                     cbuf + (size_t)(b * LL + p + 1) * DD, q, tid & 127);
    }
    if ((tid & 63) == 0) red_s[tid >> 6] = w;
    __syncthreads();
    if ((tid == 0 || tid == 128) && valid) {
        int base = tid >> 6;
        scores_g[b * NSTEP + p] = red_s[base] + red_s[base + 1];
    }
}

// ---------------------------------------------------------------------------
// stepA: 64 blocks (one per batch). rescore -> argmax -> merge -> hout (+bf16
// hi/lo split for the MFMA stepB) ; shift per-batch state (global).
// ---------------------------------------------------------------------------
__global__ __launch_bounds__(256) void stepA_k(
    int i, const int* __restrict__ length, float* __restrict__ cbuf,
    const float* __restrict__ acache, const float* __restrict__ bcache,
    float* __restrict__ hout, unsigned short* __restrict__ hh,
    unsigned short* __restrict__ hl, float* __restrict__ scores_g,
    int* __restrict__ seq_g, int* __restrict__ kp_g, int* __restrict__ msel,
    const float* __restrict__ compb, const float* __restrict__ q, float* __restrict__ out) {
    __shared__ float red_s[4];
    __shared__ float sc_l[32];
    __shared__ int seq_l[32];
    __shared__ int k_sh;
    const int tid = threadIdx.x;
    const int b = blockIdx.x;
    const int lane7 = tid & 127;
    const int lenb = length[b];
    const int ncand = NSTEP - i;

    if (i == 0) {
        if (tid < LL) seq_l[tid] = tid;
    } else {
        if (tid < LL - i) seq_l[tid] = seq_g[b * 32 + tid];
    }
    if (tid < ncand) sc_l[tid] = scores_g[b * NSTEP + tid];
    __syncthreads();
    const int kp = (i > 0) ? kp_g[b] : 0;

    if (i > 0 && i < lenb) {  // rescore candidates kp-1, kp (half-block each)
        int p = (tid < 128) ? (kp - 1) : kp;
        bool valid = (p >= 0) && (p < ncand);
        float w = 0.f;
        if (valid) {
            int sl = seq_l[p], sr = seq_l[p + 1];
            const float* ar = acache + (size_t)(b * LL + sl) * GG;
            const float* br = bcache + (size_t)(b * LL + sr) * GG;
            const float* cl = cbuf + (size_t)(b * LL + sl) * DD;
            const float* cr = cbuf + (size_t)(b * LL + sr) * DD;
#pragma unroll
            for (int pass = 0; pass < 2; ++pass) {
                int d = pass * 256 + lane7 * 2;
                float nh[2], nc[2];
                gate2n(ar, br, compb, cl, cr, d, nh, nc);
                float2 Q = *(const float2*)(q + d);
                w += nh[0] * Q.x + nh[1] * Q.y;
            }
#pragma unroll
            for (int off = 32; off; off >>= 1) w += __shfl_down(w, off);
        }
        if ((tid & 63) == 0) red_s[tid >> 6] = w;
        __syncthreads();
        if (tid == 0) {
            if (kp - 1 >= 0) sc_l[kp - 1] = red_s[0] + red_s[1];
            if (kp < ncand) sc_l[kp] = red_s[2] + red_s[3];
        }
        __syncthreads();
    }

    if (i + 1 < lenb) {
        if (tid == 0) {
            const int vmax = lenb - i - 2;
            int k = 0;
            float best = sc_l[0];
            for (int pp = 1; pp <= vmax; ++pp)
                if (sc_l[pp] > best) { best = sc_l[pp]; k = pp; }
            k_sh = k;
        }
        __syncthreads();
        const int k = k_sh;
        const int sl = seq_l[k], sr = seq_l[k + 1];
        const float* ar = acache + (size_t)(b * LL + sl) * GG;
        const float* br = bcache + (size_t)(b * LL + sr) * GG;
        const float* cl = cbuf + (size_t)(b * LL + sl) * DD;
        const float* cr = cbuf + (size_t)(b * LL + sr) * DD;
        {
            const int d = 2 * tid;
            float nh[2], nc[2];
            gate2n(ar, br, compb, cl, cr, d, nh, nc);
            *(float2*)(cbuf + (size_t)(b * LL + sl) * DD + d) = make_float2(nc[0], nc[1]);
            *(float2*)(hout + (size_t)b * DD + d) = make_float2(nh[0], nh[1]);
            // bf16 hi/lo split for stepB's MFMA A-operand
            ushort2 hv, lv;
            hv.x = f2bf(nh[0]); lv.x = f2bf(nh[0] - bf2f(hv.x));
            hv.y = f2bf(nh[1]); lv.y = f2bf(nh[1] - bf2f(hv.y));
            *(ushort2*)(hh + (size_t)b * DD + d) = hv;
            *(ushort2*)(hl + (size_t)b * DD + d) = lv;
            if (i == NSTEP - 1)
                *(float2*)(out + (size_t)b * DD + d) = make_float2(nh[0], nh[1]);
        }
        float sv = (tid + 1 < ncand) ? sc_l[tid + 1] : 0.f;
        int qv = (tid + 1 < LL - i) ? seq_l[tid + 1] : 0;
        __syncthreads();
        if (tid >= k + 1 && tid <= ncand - 2) sc_l[tid] = sv;
        if (tid >= k + 1 && tid <= LL - i - 2) seq_l[tid] = qv;
        if (tid < ncand - 1) scores_g[b * NSTEP + tid] = sc_l[tid];
        if (tid < LL - i - 1) seq_g[b * 32 + tid] = seq_l[tid];
        if (tid == 0) { kp_g[b] = k; msel[b] = sl; }
    } else if (i == NSTEP - 1) {
        const int d = 2 * tid;
        *(float2*)(out + (size_t)b * DD + d) = *(const float2*)(hout + (size_t)b * DD + d);
    }
}

// ---------------------------------------------------------------------------
// stepB via bf16x3 MFMA: O[m][n] = sum_k hout[m][k]*W[n][k], M=64, N=32/block,
// K=512. 4 waves: wave w owns m-tiles {2*(w>>1), 2*(w>>1)+1} x n-tile (w&1).
// ---------------------------------------------------------------------------
__global__ __launch_bounds__(256) void stepB_mfma(
    const unsigned short* __restrict__ hh, const unsigned short* __restrict__ hl,
    const int* __restrict__ msel,
    const unsigned short* __restrict__ Wh, const unsigned short* __restrict__ Wl,
    float* __restrict__ acache, float* __restrict__ bcache) {
    __shared__ int msel_s[BB];
    const int tid = threadIdx.x;
    const int bid = blockIdx.x;
    if (tid < BB) msel_s[tid] = msel[tid];
    __syncthreads();

    const int w = tid >> 6, lane = tid & 63;
    const int mt0 = (w >> 1) * 2;           // this wave's first m-tile
    const int nt = w & 1;                   // this wave's n-tile
    const int lr = lane & 15;
    const int kg = lane >> 4;               // k-group (8 contiguous k)
    const int n = bid * 32 + nt * 16 + lr;  // global output column

    const unsigned short* wh_row = Wh + (size_t)n * DD;
    const unsigned short* wl_row = Wl + (size_t)n * DD;
    const unsigned short* a0h_row = hh + (size_t)(mt0 * 16 + lr) * DD;
    const unsigned short* a0l_row = hl + (size_t)(mt0 * 16 + lr) * DD;
    const unsigned short* a1h_row = a0h_row + 16 * DD;
    const unsigned short* a1l_row = a0l_row + 16 * DD;

    f32x4 acc0 = {0.f, 0.f, 0.f, 0.f};
    f32x4 acc1 = {0.f, 0.f, 0.f, 0.f};

#pragma unroll 4
    for (int ks = 0; ks < 16; ++ks) {
        const int kb = ks * 32 + kg * 8;
        short8 bh = *(const short8*)(wh_row + kb);
        short8 bl = *(const short8*)(wl_row + kb);
        short8 a0h = *(const short8*)(a0h_row + kb);
        short8 a0l = *(const short8*)(a0l_row + kb);
        short8 a1h = *(const short8*)(a1h_row + kb);
        short8 a1l = *(const short8*)(a1l_row + kb);
        acc0 = __builtin_amdgcn_mfma_f32_16x16x32_bf16(a0h, bh, acc0, 0, 0, 0);
        acc1 = __builtin_amdgcn_mfma_f32_16x16x32_bf16(a1h, bh, acc1, 0, 0, 0);
        acc0 = __builtin_amdgcn_mfma_f32_16x16x32_bf16(a0l, bh, acc0, 0, 0, 0);
        acc1 = __builtin_amdgcn_mfma_f32_16x16x32_bf16(a1l, bh, acc1, 0, 0, 0);
        acc0 = __builtin_amdgcn_mfma_f32_16x16x32_bf16(a0h, bl, acc0, 0, 0, 0);
        acc1 = __builtin_amdgcn_mfma_f32_16x16x32_bf16(a1h, bl, acc1, 0, 0, 0);
    }

    // write: n fixed per lane; rows m = mt*16 + kg*4 + r, scattered by msel
#pragma unroll
    for (int t = 0; t < 2; ++t) {
        f32x4 acc = t ? acc1 : acc0;
        const int mbase = (mt0 + t) * 16 + kg * 4;
#pragma unroll
        for (int r = 0; r < 4; ++r) {
            int m = mbase + r;
            size_t row = (size_t)(m * LL + msel_s[m]);
            float* dst = (n < GG) ? (acache + row * GG + n)
                                  : (bcache + row * GG + (n - GG));
            *dst = acc[r];
        }
    }
}

// ---------------------------------------------------------------------------
extern "C" void kernel_launch(void* const* d_in, const int* in_sizes, int n_in, void* d_out,
                              int out_size, void* d_ws, size_t ws_size, hipStream_t stream) {
    const float* inp = (const float*)d_in[0];
    const int* length = (const int*)d_in[1];
    const float* word_W = (const float*)d_in[2];
    const float* word_b = (const float*)d_in[3];
    const float* comp_W = (const float*)d_in[4];
    const float* comp_b = (const float*)d_in[5];
    const float* comp_q = (const float*)d_in[6];
    float* out = (float*)d_out;

    float* ws = (float*)d_ws;
    size_t off = 0;
    float* cbuf = ws + off;   off += (size_t)BB * LL * DD;
    float* acache = ws + off; off += (size_t)BB * LL * GG;
    float* bcache = ws + off; off += (size_t)BB * LL * GG;
    float* hout = ws + off;   off += (size_t)BB * DD;
    float* scores = ws + off; off += 2048;
    int* seq_g = (int*)(ws + off); off += BB * 32;
    int* kp_g = (int*)(ws + off);  off += 64;
    int* msel = (int*)(ws + off);  off += 64;
    unsigned short* Wh = (unsigned short*)(ws + off); off += (size_t)5120 * DD / 2;
    unsigned short* Wl = (unsigned short*)(ws + off); off += (size_t)5120 * DD / 2;
    unsigned short* hh = (unsigned short*)(ws + off); off += (size_t)BB * DD / 2;
    unsigned short* hl = (unsigned short*)(ws + off); off += (size_t)BB * DD / 2;
    unsigned short* Ah = (unsigned short*)(ws + off); off += (size_t)BB * LL * DD / 2;
    unsigned short* Al = (unsigned short*)(ws + off); off += (size_t)BB * LL * DD / 2;
    (void)ws_size; (void)in_sizes; (void)n_in; (void)out_size;

    // one-time bf16 hi/lo split of comp_W (rearranged [5120][512])
    splitW_k<<<2560, 256, 0, stream>>>(comp_W, Wh, Wl);

    // word projection: h (bf16 hi/lo) , c (fp32) = split(inp @ word_W.T + word_b)
    gemm64w<<<dim3(8, 24), 256, 0, stream>>>(inp, word_W, word_b, Ah, Al, cbuf);

    // a/b caches for all 1536 items via bf16x3 MFMA
    gemm_big_mfma<<<dim3(40, 12), 256, 0, stream>>>(Ah, Al, Wh, Wl, acache, bcache);

    // initial candidate scores
    scoreall_k<<<dim3(12, 64), 256, 0, stream>>>(acache, bcache, cbuf, comp_b, comp_q, scores);

    // 23 merge steps: A (select+merge) then B (bf16x3 MFMA GEMM for merged rows)
    for (int i = 0; i < NSTEP; ++i) {
        stepA_k<<<BB, 256, 0, stream>>>(i, length, cbuf, acache, bcache, hout, hh, hl,
                                        scores, seq_g, kp_g, msel, comp_b, comp_q, out);
        if (i < NSTEP - 1) {
            stepB_mfma<<<NTILES, 256, 0, stream>>>(hh, hl, msel, Wh, Wl, acache, bcache);
        }
    }
}